// Round 1
// baseline (147.216 us; speedup 1.0000x reference)
//
#include <hip/hip_runtime.h>
#include <hip/hip_bf16.h>

#define NN 10000
#define NE 640000
#define D_IN 128
#define D_H 128
#define N_CLS 64
#define CAP 160    // per-node capacity (ushort): mean 64 sigma 8 -> +12 sigma
#define GRP 157    // coarse groups: dst>>6 (64 nodes/group)
#define CAPC 4800  // per-group coarse capacity
#define CCS 16     // coarse_cnt stride (ints): one counter per 64B line
#define SENT 10000 // sentinel node id (zero row)
#define EPB 1024
#define AB 625     // 625*1024 == 640000
#define CB 1251    // (NN+1)*32 uint2 / 256
#define WB 80      // (8192+8192+4096)/256

// ---- bf16 helpers ----
__device__ __forceinline__ float blo(unsigned u) { return __uint_as_float(u << 16); }
__device__ __forceinline__ float bhi(unsigned u) { return __uint_as_float(u & 0xffff0000u); }
__device__ __forceinline__ unsigned short f2bf(float f) {
    unsigned u = __float_as_uint(f);
    return (unsigned short)((u + 0x7fffu + ((u >> 16) & 1u)) >> 16);
}
__device__ __forceinline__ unsigned packbf(float a, float b) {
    return (unsigned)f2bf(a) | ((unsigned)f2bf(b) << 16);
}

// ---- prep_a: coarse-bucket edges + f32->bf16 feature conv + W bf16 pack ----
__global__ __launch_bounds__(256) void prep_a(const int* __restrict__ src,
                                              const int* __restrict__ dst,
                                              int* __restrict__ coarse_cnt,
                                              unsigned* __restrict__ coarse,
                                              const float* __restrict__ feat,
                                              unsigned* __restrict__ hb0,
                                              const float* __restrict__ W0,
                                              const float* __restrict__ W1,
                                              const float* __restrict__ W2,
                                              unsigned* __restrict__ wb0,
                                              unsigned* __restrict__ wb1,
                                              unsigned* __restrict__ wb2) {
    int bid = blockIdx.x;
    if (bid >= AB + CB) {   // ---- W pack ----
        int t = (bid - AB - CB) * 256 + threadIdx.x;
        if (t < 8192) {
            int kp = t >> 7, j = t & 127;
            wb0[t] = packbf(W0[(2 * kp) * 128 + j], W0[(2 * kp + 1) * 128 + j]);
        } else if (t < 16384) {
            int tt = t - 8192, kp = tt >> 7, j = tt & 127;
            wb1[tt] = packbf(W1[(2 * kp) * 128 + j], W1[(2 * kp + 1) * 128 + j]);
        } else if (t < 20480) {
            int tt = t - 16384, kp = tt >> 6, j = tt & 63;
            wb2[tt] = packbf(W2[(2 * kp) * 64 + j], W2[(2 * kp + 1) * 64 + j]);
        }
        return;
    }
    if (bid >= AB) {   // ---- feature conv ----
        int t = (bid - AB) * 256 + threadIdx.x;
        if (t < NN * 32) {
            float4 f = ((const float4*)feat)[t];
            ((uint2*)hb0)[t] = make_uint2(packbf(f.x, f.y), packbf(f.z, f.w));
        } else if (t < (NN + 1) * 32) {
            ((uint2*)hb0)[t] = make_uint2(0u, 0u);
        }
        return;
    }
    __shared__ unsigned stage[EPB];
    __shared__ int hist[GRP], gbase[GRP], cur[GRP];
    const int t = threadIdx.x;
    for (int i = t; i < GRP; i += 256) hist[i] = 0;
    __syncthreads();
    const int e0 = bid * EPB;
    for (int i = t; i < EPB; i += 256) {
        int s = src[e0 + i];
        int d = dst[e0 + i];
        stage[i] = (unsigned)s | ((unsigned)d << 16);
        atomicAdd(&hist[d >> 6], 1);
    }
    __syncthreads();
    for (int i = t; i < GRP; i += 256) {
        gbase[i] = atomicAdd(&coarse_cnt[i * CCS], hist[i]);
        cur[i] = 0;
    }
    __syncthreads();
    for (int i = t; i < EPB; i += 256) {
        unsigned u = stage[i];
        int g = u >> 22;
        int r = atomicAdd(&cur[g], 1);
        coarse[g * CAPC + gbase[g] + r] = u;
    }
}

// ---- prep_b: per-group scatter into LDS-staged colbuf, pad to x32, coalesced copy-out ----
__global__ __launch_bounds__(1024) void prep_b(const int* __restrict__ coarse_cnt,
                                               const unsigned* __restrict__ coarse,
                                               int* __restrict__ cnt,
                                               unsigned short* __restrict__ colbuf) {
    __shared__ int cur[64];
    __shared__ unsigned short sbuf[64][CAP];   // 20480 B LDS stage for this group
    const int g = blockIdx.x;
    const int t = threadIdx.x;
    if (t < 64) cur[t] = 0;
    __syncthreads();
    const int m = coarse_cnt[g * CCS];
    const unsigned* cb = coarse + g * CAPC;
    for (int i = t; i < m; i += 1024) {
        unsigned u = cb[i];
        int s = (int)(u & 0xFFFFu);
        int dl = (int)(u >> 16) - (g << 6);
        int r = atomicAdd(&cur[dl], 1);
        sbuf[dl][r] = (unsigned short)s;       // 2B scatter stays in LDS
    }
    __syncthreads();
    if (t < 64) {
        int n = (g << 6) + t;
        if (n < NN) {
            int c = cur[t];
            int pad = (32 - (c & 31)) & 31;    // pad to x32 for the unrolled gather
            for (int k = 0; k < pad; ++k) sbuf[t][c + k] = (unsigned short)SENT;
            cnt[n] = c + pad;
        }
    }
    __syncthreads();
    // coalesced copy-out: 64 nodes x (CAP/8 = 20) uint4
    const uint4* s4 = (const uint4*)sbuf;
    for (int idx = t; idx < 64 * (CAP / 8); idx += 1024) {
        int node = (g << 6) + (idx / (CAP / 8));
        if (node < NN)
            ((uint4*)colbuf)[(size_t)node * (CAP / 8) + (idx % (CAP / 8))] = s4[idx];
    }
}

// ---- fused layer: 1 node/wave, 32 rows/iter (8 gathers in flight) + id prefetch ----
template <int J, bool LAST>
__global__ __launch_bounds__(256, 4) void gin_layer(const uint4* __restrict__ hb4,
                                                    const int* __restrict__ cnt,
                                                    const unsigned short* __restrict__ colbuf,
                                                    const unsigned* __restrict__ Wb,
                                                    unsigned short* __restrict__ outb,
                                                    float* __restrict__ outf) {
    constexpr int M = 4;
    __shared__ float xs[M][D_H];
    const int base = blockIdx.x * M;
    const int tid = threadIdx.x;
    const int wave = tid >> 6;
    const int lane = tid & 63;
    const int sub = lane >> 4;
    const int off = lane & 15;

    // wave-uniform node id -> scalar (SMEM) path for count/id loads
    const int n = __builtin_amdgcn_readfirstlane(base + wave);
    float a0, a1, a2, a3, a4, a5, a6, a7;
    if (sub == 0) {           // own row (eps=0: h + agg)
        uint4 u = hb4[n * 16 + off];
        a0 = blo(u.x); a1 = bhi(u.x); a2 = blo(u.y); a3 = bhi(u.y);
        a4 = blo(u.z); a5 = bhi(u.z); a6 = blo(u.w); a7 = bhi(u.w);
    } else {
        a0 = a1 = a2 = a3 = a4 = a5 = a6 = a7 = 0.f;
    }
    const int NCH = __builtin_amdgcn_readfirstlane(cnt[n]) >> 5;   // 32-row chunks
    const uint2* cl = (const uint2*)(colbuf + n * CAP);
    const int sh = (sub & 1) << 4;   // 16-bit half select
    // preload ids for chunk 0 (wave-uniform 64B -> one s_load_dwordx16)
    uint2 p0 = cl[0], p1 = cl[1], p2 = cl[2], p3 = cl[3];
    uint2 p4 = cl[4], p5 = cl[5], p6 = cl[6], p7 = cl[7];
    for (int c = 0; c < NCH; ++c) {
        unsigned w0 = (sub & 2) ? p0.y : p0.x;
        unsigned w1 = (sub & 2) ? p1.y : p1.x;
        unsigned w2 = (sub & 2) ? p2.y : p2.x;
        unsigned w3 = (sub & 2) ? p3.y : p3.x;
        unsigned w4 = (sub & 2) ? p4.y : p4.x;
        unsigned w5 = (sub & 2) ? p5.y : p5.x;
        unsigned w6 = (sub & 2) ? p6.y : p6.x;
        unsigned w7 = (sub & 2) ? p7.y : p7.x;
        int s0 = (int)((w0 >> sh) & 0xffffu);
        int s1 = (int)((w1 >> sh) & 0xffffu);
        int s2 = (int)((w2 >> sh) & 0xffffu);
        int s3 = (int)((w3 >> sh) & 0xffffu);
        int s4 = (int)((w4 >> sh) & 0xffffu);
        int s5 = (int)((w5 >> sh) & 0xffffu);
        int s6 = (int)((w6 >> sh) & 0xffffu);
        int s7 = (int)((w7 >> sh) & 0xffffu);
        uint4 u0 = hb4[s0 * 16 + off];
        uint4 u1 = hb4[s1 * 16 + off];
        uint4 u2 = hb4[s2 * 16 + off];
        uint4 u3 = hb4[s3 * 16 + off];
        uint4 u4 = hb4[s4 * 16 + off];
        uint4 u5 = hb4[s5 * 16 + off];
        uint4 u6 = hb4[s6 * 16 + off];
        uint4 u7 = hb4[s7 * 16 + off];
        // prefetch next chunk's ids while gathers are in flight
        // (safe over-read: stays inside this node's CAP=160-ushort region)
        {
            const uint2* nx = cl + 8 * (c + 1);
            p0 = nx[0]; p1 = nx[1]; p2 = nx[2]; p3 = nx[3];
            p4 = nx[4]; p5 = nx[5]; p6 = nx[6]; p7 = nx[7];
        }
        a0 += ((blo(u0.x) + blo(u1.x)) + (blo(u2.x) + blo(u3.x)))
            + ((blo(u4.x) + blo(u5.x)) + (blo(u6.x) + blo(u7.x)));
        a1 += ((bhi(u0.x) + bhi(u1.x)) + (bhi(u2.x) + bhi(u3.x)))
            + ((bhi(u4.x) + bhi(u5.x)) + (bhi(u6.x) + bhi(u7.x)));
        a2 += ((blo(u0.y) + blo(u1.y)) + (blo(u2.y) + blo(u3.y)))
            + ((blo(u4.y) + blo(u5.y)) + (blo(u6.y) + blo(u7.y)));
        a3 += ((bhi(u0.y) + bhi(u1.y)) + (bhi(u2.y) + bhi(u3.y)))
            + ((bhi(u4.y) + bhi(u5.y)) + (bhi(u6.y) + bhi(u7.y)));
        a4 += ((blo(u0.z) + blo(u1.z)) + (blo(u2.z) + blo(u3.z)))
            + ((blo(u4.z) + blo(u5.z)) + (blo(u6.z) + blo(u7.z)));
        a5 += ((bhi(u0.z) + bhi(u1.z)) + (bhi(u2.z) + bhi(u3.z)))
            + ((bhi(u4.z) + bhi(u5.z)) + (bhi(u6.z) + bhi(u7.z)));
        a6 += ((blo(u0.w) + blo(u1.w)) + (blo(u2.w) + blo(u3.w)))
            + ((blo(u4.w) + blo(u5.w)) + (blo(u6.w) + blo(u7.w)));
        a7 += ((bhi(u0.w) + bhi(u1.w)) + (bhi(u2.w) + bhi(u3.w)))
            + ((bhi(u4.w) + bhi(u5.w)) + (bhi(u6.w) + bhi(u7.w)));
    }
    a0 += __shfl_xor(a0, 16); a0 += __shfl_xor(a0, 32);
    a1 += __shfl_xor(a1, 16); a1 += __shfl_xor(a1, 32);
    a2 += __shfl_xor(a2, 16); a2 += __shfl_xor(a2, 32);
    a3 += __shfl_xor(a3, 16); a3 += __shfl_xor(a3, 32);
    a4 += __shfl_xor(a4, 16); a4 += __shfl_xor(a4, 32);
    a5 += __shfl_xor(a5, 16); a5 += __shfl_xor(a5, 32);
    a6 += __shfl_xor(a6, 16); a6 += __shfl_xor(a6, 32);
    a7 += __shfl_xor(a7, 16); a7 += __shfl_xor(a7, 32);
    if (sub == 0) {
        *(float4*)&xs[wave][8 * off]     = make_float4(a0, a1, a2, a3);
        *(float4*)&xs[wave][8 * off + 4] = make_float4(a4, a5, a6, a7);
    }
    __syncthreads();

    // ---- GEMM: W in bf16 k-pairs ----
    constexpr int G = 256 / J;
    constexpr int NM = M / G;
    const int gq = tid / J;
    const int j = tid % J;
    const int mbase = gq * NM;
    float acc[NM];
#pragma unroll
    for (int m = 0; m < NM; ++m) acc[m] = 0.f;
    for (int k = 0; k < D_H; k += 4) {
        unsigned wp0 = Wb[(k >> 1) * J + j];
        unsigned wp1 = Wb[((k >> 1) + 1) * J + j];
        float w0 = blo(wp0), w1 = bhi(wp0), w2 = blo(wp1), w3 = bhi(wp1);
#pragma unroll
        for (int m = 0; m < NM; ++m) {
            float4 xv = *(const float4*)&xs[mbase + m][k];
            acc[m] += xv.x * w0 + xv.y * w1 + xv.z * w2 + xv.w * w3;
        }
    }
#pragma unroll
    for (int m = 0; m < NM; ++m) {
        int n2 = base + mbase + m;
        if (LAST) __builtin_nontemporal_store(acc[m], &outf[(size_t)n2 * J + j]);
        else      __builtin_nontemporal_store(f2bf(acc[m]), &outb[(size_t)n2 * J + j]);
    }
    if (!LAST && blockIdx.x == 0 && tid < 32) {
        ((uint2*)(outb + (size_t)SENT * D_H))[tid] = make_uint2(0u, 0u);
    }
}

extern "C" void kernel_launch(void* const* d_in, const int* in_sizes, int n_in,
                              void* d_out, int out_size, void* d_ws, size_t ws_size,
                              hipStream_t stream) {
    const float* feat = (const float*)d_in[0];
    const float* W0   = (const float*)d_in[1];
    const float* W1   = (const float*)d_in[2];
    const float* W2   = (const float*)d_in[3];
    const int*   src  = (const int*)d_in[4];
    const int*   dst  = (const int*)d_in[5];
    float* out = (float*)d_out;

    int* coarse_cnt        = (int*)d_ws;                          // GRP*CCS ints
    int* cnt               = coarse_cnt + GRP * CCS;              // NN (+8 align pad)
    unsigned short* colbuf = (unsigned short*)(cnt + NN + 8);     // NN*CAP
    unsigned* coarse       = (unsigned*)(colbuf + (size_t)NN * CAP);  // GRP*CAPC
    unsigned* hb0          = coarse + (size_t)GRP * CAPC;         // (NN+1)*64
    unsigned* hb1          = hb0 + (size_t)(NN + 1) * 64;
    unsigned* hb2          = hb1 + (size_t)(NN + 1) * 64;
    unsigned* wb0          = hb2 + (size_t)(NN + 1) * 64;         // 8192
    unsigned* wb1          = wb0 + 8192;                          // 8192
    unsigned* wb2          = wb1 + 8192;                          // 4096

    hipMemsetAsync(coarse_cnt, 0, GRP * CCS * sizeof(int), stream);
    prep_a<<<AB + CB + WB, 256, 0, stream>>>(src, dst, coarse_cnt, coarse, feat, hb0,
                                             W0, W1, W2, wb0, wb1, wb2);
    prep_b<<<GRP, 1024, 0, stream>>>(coarse_cnt, coarse, cnt, colbuf);

    gin_layer<D_H, false><<<NN / 4, 256, 0, stream>>>((const uint4*)hb0, cnt, colbuf, wb0,
                                                      (unsigned short*)hb1, nullptr);
    gin_layer<D_H, false><<<NN / 4, 256, 0, stream>>>((const uint4*)hb1, cnt, colbuf, wb1,
                                                      (unsigned short*)hb2, nullptr);
    gin_layer<N_CLS, true><<<NN / 4, 256, 0, stream>>>((const uint4*)hb2, cnt, colbuf, wb2,
                                                       nullptr, out);
}

// Round 3
// 142.918 us; speedup vs baseline: 1.0301x; 1.0301x over previous
//
#include <hip/hip_runtime.h>
#include <hip/hip_bf16.h>

#define NN 10000
#define NE 640000
#define D_IN 128
#define D_H 128
#define N_CLS 64
#define CAP 160    // per-node capacity (ushort): mean 64 sigma 8 -> +12 sigma
#define GRP 157    // coarse groups: dst>>6 (64 nodes/group)
#define CAPC 4800  // per-group coarse capacity
#define CCS 16     // coarse_cnt stride (ints): one counter per 64B line
#define SENT 10000 // sentinel node id (zero row)
#define EPB 1024
#define AB 625     // 625*1024 == 640000
#define CB 1251    // (NN+1)*32 uint2 / 256
#define WB 80      // (8192+8192+4096)/256

// ---- bf16 helpers ----
__device__ __forceinline__ float blo(unsigned u) { return __uint_as_float(u << 16); }
__device__ __forceinline__ float bhi(unsigned u) { return __uint_as_float(u & 0xffff0000u); }
__device__ __forceinline__ unsigned short f2bf(float f) {
    unsigned u = __float_as_uint(f);
    return (unsigned short)((u + 0x7fffu + ((u >> 16) & 1u)) >> 16);
}
__device__ __forceinline__ unsigned packbf(float a, float b) {
    return (unsigned)f2bf(a) | ((unsigned)f2bf(b) << 16);
}

// ---- prep_a: coarse-bucket edges + f32->bf16 feature conv + W bf16 pack ----
__global__ __launch_bounds__(256) void prep_a(const int* __restrict__ src,
                                              const int* __restrict__ dst,
                                              int* __restrict__ coarse_cnt,
                                              unsigned* __restrict__ coarse,
                                              const float* __restrict__ feat,
                                              unsigned* __restrict__ hb0,
                                              const float* __restrict__ W0,
                                              const float* __restrict__ W1,
                                              const float* __restrict__ W2,
                                              unsigned* __restrict__ wb0,
                                              unsigned* __restrict__ wb1,
                                              unsigned* __restrict__ wb2) {
    int bid = blockIdx.x;
    if (bid >= AB + CB) {   // ---- W pack ----
        int t = (bid - AB - CB) * 256 + threadIdx.x;
        if (t < 8192) {
            int kp = t >> 7, j = t & 127;
            wb0[t] = packbf(W0[(2 * kp) * 128 + j], W0[(2 * kp + 1) * 128 + j]);
        } else if (t < 16384) {
            int tt = t - 8192, kp = tt >> 7, j = tt & 127;
            wb1[tt] = packbf(W1[(2 * kp) * 128 + j], W1[(2 * kp + 1) * 128 + j]);
        } else if (t < 20480) {
            int tt = t - 16384, kp = tt >> 6, j = tt & 63;
            wb2[tt] = packbf(W2[(2 * kp) * 64 + j], W2[(2 * kp + 1) * 64 + j]);
        }
        return;
    }
    if (bid >= AB) {   // ---- feature conv ----
        int t = (bid - AB) * 256 + threadIdx.x;
        if (t < NN * 32) {
            float4 f = ((const float4*)feat)[t];
            ((uint2*)hb0)[t] = make_uint2(packbf(f.x, f.y), packbf(f.z, f.w));
        } else if (t < (NN + 1) * 32) {
            ((uint2*)hb0)[t] = make_uint2(0u, 0u);
        }
        return;
    }
    __shared__ unsigned stage[EPB];
    __shared__ int hist[GRP], gbase[GRP], cur[GRP];
    const int t = threadIdx.x;
    for (int i = t; i < GRP; i += 256) hist[i] = 0;
    __syncthreads();
    const int e0 = bid * EPB;
    for (int i = t; i < EPB; i += 256) {
        int s = src[e0 + i];
        int d = dst[e0 + i];
        stage[i] = (unsigned)s | ((unsigned)d << 16);
        atomicAdd(&hist[d >> 6], 1);
    }
    __syncthreads();
    for (int i = t; i < GRP; i += 256) {
        gbase[i] = atomicAdd(&coarse_cnt[i * CCS], hist[i]);
        cur[i] = 0;
    }
    __syncthreads();
    for (int i = t; i < EPB; i += 256) {
        unsigned u = stage[i];
        int g = u >> 22;
        int r = atomicAdd(&cur[g], 1);
        coarse[g * CAPC + gbase[g] + r] = u;
    }
}

// ---- prep_b: per-group scatter into LDS-staged colbuf, pad to x32, coalesced copy-out ----
__global__ __launch_bounds__(1024) void prep_b(const int* __restrict__ coarse_cnt,
                                               const unsigned* __restrict__ coarse,
                                               int* __restrict__ cnt,
                                               unsigned short* __restrict__ colbuf) {
    __shared__ int cur[64];
    __shared__ unsigned short sbuf[64][CAP];   // 20480 B LDS stage for this group
    const int g = blockIdx.x;
    const int t = threadIdx.x;
    if (t < 64) cur[t] = 0;
    __syncthreads();
    const int m = coarse_cnt[g * CCS];
    const unsigned* cb = coarse + g * CAPC;
    for (int i = t; i < m; i += 1024) {
        unsigned u = cb[i];
        int s = (int)(u & 0xFFFFu);
        int dl = (int)(u >> 16) - (g << 6);
        int r = atomicAdd(&cur[dl], 1);
        sbuf[dl][r] = (unsigned short)s;       // 2B scatter stays in LDS
    }
    __syncthreads();
    if (t < 64) {
        int n = (g << 6) + t;
        if (n < NN) {
            int c = cur[t];
            int pad = (32 - (c & 31)) & 31;    // pad to x32 for the unrolled gather
            for (int k = 0; k < pad; ++k) sbuf[t][c + k] = (unsigned short)SENT;
            cnt[n] = c + pad;
        }
    }
    __syncthreads();
    // coalesced copy-out: 64 nodes x (CAP/8 = 20) uint4
    const uint4* s4 = (const uint4*)sbuf;
    for (int idx = t; idx < 64 * (CAP / 8); idx += 1024) {
        int node = (g << 6) + (idx / (CAP / 8));
        if (node < NN)
            ((uint4*)colbuf)[(size_t)node * (CAP / 8) + (idx % (CAP / 8))] = s4[idx];
    }
}

// ---- layer 1: gather + (h+agg)@W0 -> bf16 ----
__global__ __launch_bounds__(256, 4) void gin_layer1(const uint4* __restrict__ hb4,
                                                     const int* __restrict__ cnt,
                                                     const unsigned short* __restrict__ colbuf,
                                                     const unsigned* __restrict__ Wb,
                                                     unsigned short* __restrict__ outb) {
    constexpr int M = 4;
    __shared__ float xs[M][D_H];
    const int base = blockIdx.x * M;
    const int tid = threadIdx.x;
    const int wave = tid >> 6;
    const int lane = tid & 63;
    const int sub = lane >> 4;
    const int off = lane & 15;

    const int n = __builtin_amdgcn_readfirstlane(base + wave);
    float a0, a1, a2, a3, a4, a5, a6, a7;
    if (sub == 0) {
        uint4 u = hb4[n * 16 + off];
        a0 = blo(u.x); a1 = bhi(u.x); a2 = blo(u.y); a3 = bhi(u.y);
        a4 = blo(u.z); a5 = bhi(u.z); a6 = blo(u.w); a7 = bhi(u.w);
    } else {
        a0 = a1 = a2 = a3 = a4 = a5 = a6 = a7 = 0.f;
    }
    const int NCH = __builtin_amdgcn_readfirstlane(cnt[n]) >> 5;
    const uint2* cl = (const uint2*)(colbuf + n * CAP);
    const int sh = (sub & 1) << 4;
    uint2 p0 = cl[0], p1 = cl[1], p2 = cl[2], p3 = cl[3];
    uint2 p4 = cl[4], p5 = cl[5], p6 = cl[6], p7 = cl[7];
    for (int c = 0; c < NCH; ++c) {
        unsigned w0 = (sub & 2) ? p0.y : p0.x;
        unsigned w1 = (sub & 2) ? p1.y : p1.x;
        unsigned w2 = (sub & 2) ? p2.y : p2.x;
        unsigned w3 = (sub & 2) ? p3.y : p3.x;
        unsigned w4 = (sub & 2) ? p4.y : p4.x;
        unsigned w5 = (sub & 2) ? p5.y : p5.x;
        unsigned w6 = (sub & 2) ? p6.y : p6.x;
        unsigned w7 = (sub & 2) ? p7.y : p7.x;
        int s0 = (int)((w0 >> sh) & 0xffffu);
        int s1 = (int)((w1 >> sh) & 0xffffu);
        int s2 = (int)((w2 >> sh) & 0xffffu);
        int s3 = (int)((w3 >> sh) & 0xffffu);
        int s4 = (int)((w4 >> sh) & 0xffffu);
        int s5 = (int)((w5 >> sh) & 0xffffu);
        int s6 = (int)((w6 >> sh) & 0xffffu);
        int s7 = (int)((w7 >> sh) & 0xffffu);
        uint4 u0 = hb4[s0 * 16 + off];
        uint4 u1 = hb4[s1 * 16 + off];
        uint4 u2 = hb4[s2 * 16 + off];
        uint4 u3 = hb4[s3 * 16 + off];
        uint4 u4 = hb4[s4 * 16 + off];
        uint4 u5 = hb4[s5 * 16 + off];
        uint4 u6 = hb4[s6 * 16 + off];
        uint4 u7 = hb4[s7 * 16 + off];
        {
            const uint2* nx = cl + 8 * (c + 1);
            p0 = nx[0]; p1 = nx[1]; p2 = nx[2]; p3 = nx[3];
            p4 = nx[4]; p5 = nx[5]; p6 = nx[6]; p7 = nx[7];
        }
        a0 += ((blo(u0.x) + blo(u1.x)) + (blo(u2.x) + blo(u3.x)))
            + ((blo(u4.x) + blo(u5.x)) + (blo(u6.x) + blo(u7.x)));
        a1 += ((bhi(u0.x) + bhi(u1.x)) + (bhi(u2.x) + bhi(u3.x)))
            + ((bhi(u4.x) + bhi(u5.x)) + (bhi(u6.x) + bhi(u7.x)));
        a2 += ((blo(u0.y) + blo(u1.y)) + (blo(u2.y) + blo(u3.y)))
            + ((blo(u4.y) + blo(u5.y)) + (blo(u6.y) + blo(u7.y)));
        a3 += ((bhi(u0.y) + bhi(u1.y)) + (bhi(u2.y) + bhi(u3.y)))
            + ((bhi(u4.y) + bhi(u5.y)) + (bhi(u6.y) + bhi(u7.y)));
        a4 += ((blo(u0.z) + blo(u1.z)) + (blo(u2.z) + blo(u3.z)))
            + ((blo(u4.z) + blo(u5.z)) + (blo(u6.z) + blo(u7.z)));
        a5 += ((bhi(u0.z) + bhi(u1.z)) + (bhi(u2.z) + bhi(u3.z)))
            + ((bhi(u4.z) + bhi(u5.z)) + (bhi(u6.z) + bhi(u7.z)));
        a6 += ((blo(u0.w) + blo(u1.w)) + (blo(u2.w) + blo(u3.w)))
            + ((blo(u4.w) + blo(u5.w)) + (blo(u6.w) + blo(u7.w)));
        a7 += ((bhi(u0.w) + bhi(u1.w)) + (bhi(u2.w) + bhi(u3.w)))
            + ((bhi(u4.w) + bhi(u5.w)) + (bhi(u6.w) + bhi(u7.w)));
    }
    a0 += __shfl_xor(a0, 16); a0 += __shfl_xor(a0, 32);
    a1 += __shfl_xor(a1, 16); a1 += __shfl_xor(a1, 32);
    a2 += __shfl_xor(a2, 16); a2 += __shfl_xor(a2, 32);
    a3 += __shfl_xor(a3, 16); a3 += __shfl_xor(a3, 32);
    a4 += __shfl_xor(a4, 16); a4 += __shfl_xor(a4, 32);
    a5 += __shfl_xor(a5, 16); a5 += __shfl_xor(a5, 32);
    a6 += __shfl_xor(a6, 16); a6 += __shfl_xor(a6, 32);
    a7 += __shfl_xor(a7, 16); a7 += __shfl_xor(a7, 32);
    if (sub == 0) {
        *(float4*)&xs[wave][8 * off]     = make_float4(a0, a1, a2, a3);
        *(float4*)&xs[wave][8 * off + 4] = make_float4(a4, a5, a6, a7);
    }
    __syncthreads();

    // ---- GEMM: (h+agg)@W0, W in bf16 k-pairs ----
    constexpr int J = D_H;
    constexpr int G = 256 / J;   // 2
    constexpr int NM = M / G;    // 2
    const int gq = tid / J;
    const int j = tid % J;
    const int mbase = gq * NM;
    float acc[NM];
#pragma unroll
    for (int m = 0; m < NM; ++m) acc[m] = 0.f;
    for (int k = 0; k < D_H; k += 4) {
        unsigned wp0 = Wb[(k >> 1) * J + j];
        unsigned wp1 = Wb[((k >> 1) + 1) * J + j];
        float w0 = blo(wp0), w1 = bhi(wp0), w2 = blo(wp1), w3 = bhi(wp1);
#pragma unroll
        for (int m = 0; m < NM; ++m) {
            float4 xv = *(const float4*)&xs[mbase + m][k];
            acc[m] += xv.x * w0 + xv.y * w1 + xv.z * w2 + xv.w * w3;
        }
    }
#pragma unroll
    for (int m = 0; m < NM; ++m) {
        int n2 = base + mbase + m;
        outb[(size_t)n2 * J + j] = f2bf(acc[m]);
    }
    if (blockIdx.x == 0 && tid < 32) {
        ((uint2*)(outb + (size_t)SENT * D_H))[tid] = make_uint2(0u, 0u);
    }
}

// ---- layer 2 fused with layer-3 transform:
//      t = ((h1+agg)@W1)@W2  (f32 intermediate in LDS, single bf16 rounding) ----
__global__ __launch_bounds__(256, 4) void gin_mid(const uint4* __restrict__ hb4,
                                                  const int* __restrict__ cnt,
                                                  const unsigned short* __restrict__ colbuf,
                                                  const unsigned* __restrict__ Wb1,
                                                  const unsigned* __restrict__ Wb2,
                                                  unsigned short* __restrict__ tb) {
    constexpr int M = 4;
    __shared__ float xs[M][D_H];
    __shared__ float ys[M][136];   // stride 136: 16B-aligned float4, bank-shifted rows
    const int base = blockIdx.x * M;
    const int tid = threadIdx.x;
    const int wave = tid >> 6;
    const int lane = tid & 63;
    const int sub = lane >> 4;
    const int off = lane & 15;

    const int n = __builtin_amdgcn_readfirstlane(base + wave);
    float a0, a1, a2, a3, a4, a5, a6, a7;
    if (sub == 0) {
        uint4 u = hb4[n * 16 + off];
        a0 = blo(u.x); a1 = bhi(u.x); a2 = blo(u.y); a3 = bhi(u.y);
        a4 = blo(u.z); a5 = bhi(u.z); a6 = blo(u.w); a7 = bhi(u.w);
    } else {
        a0 = a1 = a2 = a3 = a4 = a5 = a6 = a7 = 0.f;
    }
    const int NCH = __builtin_amdgcn_readfirstlane(cnt[n]) >> 5;
    const uint2* cl = (const uint2*)(colbuf + n * CAP);
    const int sh = (sub & 1) << 4;
    uint2 p0 = cl[0], p1 = cl[1], p2 = cl[2], p3 = cl[3];
    uint2 p4 = cl[4], p5 = cl[5], p6 = cl[6], p7 = cl[7];
    for (int c = 0; c < NCH; ++c) {
        unsigned w0 = (sub & 2) ? p0.y : p0.x;
        unsigned w1 = (sub & 2) ? p1.y : p1.x;
        unsigned w2 = (sub & 2) ? p2.y : p2.x;
        unsigned w3 = (sub & 2) ? p3.y : p3.x;
        unsigned w4 = (sub & 2) ? p4.y : p4.x;
        unsigned w5 = (sub & 2) ? p5.y : p5.x;
        unsigned w6 = (sub & 2) ? p6.y : p6.x;
        unsigned w7 = (sub & 2) ? p7.y : p7.x;
        int s0 = (int)((w0 >> sh) & 0xffffu);
        int s1 = (int)((w1 >> sh) & 0xffffu);
        int s2 = (int)((w2 >> sh) & 0xffffu);
        int s3 = (int)((w3 >> sh) & 0xffffu);
        int s4 = (int)((w4 >> sh) & 0xffffu);
        int s5 = (int)((w5 >> sh) & 0xffffu);
        int s6 = (int)((w6 >> sh) & 0xffffu);
        int s7 = (int)((w7 >> sh) & 0xffffu);
        uint4 u0 = hb4[s0 * 16 + off];
        uint4 u1 = hb4[s1 * 16 + off];
        uint4 u2 = hb4[s2 * 16 + off];
        uint4 u3 = hb4[s3 * 16 + off];
        uint4 u4 = hb4[s4 * 16 + off];
        uint4 u5 = hb4[s5 * 16 + off];
        uint4 u6 = hb4[s6 * 16 + off];
        uint4 u7 = hb4[s7 * 16 + off];
        {
            const uint2* nx = cl + 8 * (c + 1);
            p0 = nx[0]; p1 = nx[1]; p2 = nx[2]; p3 = nx[3];
            p4 = nx[4]; p5 = nx[5]; p6 = nx[6]; p7 = nx[7];
        }
        a0 += ((blo(u0.x) + blo(u1.x)) + (blo(u2.x) + blo(u3.x)))
            + ((blo(u4.x) + blo(u5.x)) + (blo(u6.x) + blo(u7.x)));
        a1 += ((bhi(u0.x) + bhi(u1.x)) + (bhi(u2.x) + bhi(u3.x)))
            + ((bhi(u4.x) + bhi(u5.x)) + (bhi(u6.x) + bhi(u7.x)));
        a2 += ((blo(u0.y) + blo(u1.y)) + (blo(u2.y) + blo(u3.y)))
            + ((blo(u4.y) + blo(u5.y)) + (blo(u6.y) + blo(u7.y)));
        a3 += ((bhi(u0.y) + bhi(u1.y)) + (bhi(u2.y) + bhi(u3.y)))
            + ((bhi(u4.y) + bhi(u5.y)) + (bhi(u6.y) + bhi(u7.y)));
        a4 += ((blo(u0.z) + blo(u1.z)) + (blo(u2.z) + blo(u3.z)))
            + ((blo(u4.z) + blo(u5.z)) + (blo(u6.z) + blo(u7.z)));
        a5 += ((bhi(u0.z) + bhi(u1.z)) + (bhi(u2.z) + bhi(u3.z)))
            + ((bhi(u4.z) + bhi(u5.z)) + (bhi(u6.z) + bhi(u7.z)));
        a6 += ((blo(u0.w) + blo(u1.w)) + (blo(u2.w) + blo(u3.w)))
            + ((blo(u4.w) + blo(u5.w)) + (blo(u6.w) + blo(u7.w)));
        a7 += ((bhi(u0.w) + bhi(u1.w)) + (bhi(u2.w) + bhi(u3.w)))
            + ((bhi(u4.w) + bhi(u5.w)) + (bhi(u6.w) + bhi(u7.w)));
    }
    a0 += __shfl_xor(a0, 16); a0 += __shfl_xor(a0, 32);
    a1 += __shfl_xor(a1, 16); a1 += __shfl_xor(a1, 32);
    a2 += __shfl_xor(a2, 16); a2 += __shfl_xor(a2, 32);
    a3 += __shfl_xor(a3, 16); a3 += __shfl_xor(a3, 32);
    a4 += __shfl_xor(a4, 16); a4 += __shfl_xor(a4, 32);
    a5 += __shfl_xor(a5, 16); a5 += __shfl_xor(a5, 32);
    a6 += __shfl_xor(a6, 16); a6 += __shfl_xor(a6, 32);
    a7 += __shfl_xor(a7, 16); a7 += __shfl_xor(a7, 32);
    if (sub == 0) {
        *(float4*)&xs[wave][8 * off]     = make_float4(a0, a1, a2, a3);
        *(float4*)&xs[wave][8 * off + 4] = make_float4(a4, a5, a6, a7);
    }
    __syncthreads();

    // ---- GEMM1: y = (h1+agg)@W1  (f32, stays in LDS) ----
    {
        constexpr int J = D_H;       // 128
        constexpr int G = 256 / J;   // 2
        constexpr int NM = M / G;    // 2
        const int gq = tid / J;
        const int j = tid % J;
        const int mbase = gq * NM;
        float acc[NM];
#pragma unroll
        for (int m = 0; m < NM; ++m) acc[m] = 0.f;
        for (int k = 0; k < D_H; k += 4) {
            unsigned wp0 = Wb1[(k >> 1) * J + j];
            unsigned wp1 = Wb1[((k >> 1) + 1) * J + j];
            float w0 = blo(wp0), w1 = bhi(wp0), w2 = blo(wp1), w3 = bhi(wp1);
#pragma unroll
            for (int m = 0; m < NM; ++m) {
                float4 xv = *(const float4*)&xs[mbase + m][k];
                acc[m] += xv.x * w0 + xv.y * w1 + xv.z * w2 + xv.w * w3;
            }
        }
#pragma unroll
        for (int m = 0; m < NM; ++m) ys[mbase + m][j] = acc[m];
    }
    __syncthreads();

    // ---- GEMM2: t = y@W2 (128->64), single bf16 rounding at the end ----
    {
        constexpr int J = N_CLS;     // 64
        const int j = tid & 63;
        const int gm = tid >> 6;     // node 0..3
        float acc = 0.f;
        for (int k = 0; k < D_H; k += 4) {
            unsigned wp0 = Wb2[(k >> 1) * J + j];
            unsigned wp1 = Wb2[((k >> 1) + 1) * J + j];
            float w0 = blo(wp0), w1 = bhi(wp0), w2 = blo(wp1), w3 = bhi(wp1);
            float4 xv = *(const float4*)&ys[gm][k];
            acc += xv.x * w0 + xv.y * w1 + xv.z * w2 + xv.w * w3;
        }
        tb[(size_t)(base + gm) * J + j] = f2bf(acc);
    }
    if (blockIdx.x == 0 && tid < 16) {
        ((uint2*)(tb + (size_t)SENT * N_CLS))[tid] = make_uint2(0u, 0u);
    }
}

// ---- layer 3: pure aggregate of 64-dim transformed rows (128B/row, 8 rows/instr) ----
__global__ __launch_bounds__(256, 4) void agg3(const uint4* __restrict__ tb4,
                                               const int* __restrict__ cnt,
                                               const unsigned short* __restrict__ colbuf,
                                               float* __restrict__ outf) {
    constexpr int M = 4;
    const int base = blockIdx.x * M;
    const int tid = threadIdx.x;
    const int wave = tid >> 6;
    const int lane = tid & 63;
    const int sub = lane >> 3;     // 0..7 : 8 rows per load instruction
    const int off = lane & 7;      // 16B slice within a 128B row

    const int n = __builtin_amdgcn_readfirstlane(base + wave);
    float a0, a1, a2, a3, a4, a5, a6, a7;
    if (sub == 0) {                // own row (eps=0)
        uint4 u = tb4[n * 8 + off];
        a0 = blo(u.x); a1 = bhi(u.x); a2 = blo(u.y); a3 = bhi(u.y);
        a4 = blo(u.z); a5 = bhi(u.z); a6 = blo(u.w); a7 = bhi(u.w);
    } else {
        a0 = a1 = a2 = a3 = a4 = a5 = a6 = a7 = 0.f;
    }
    const int NCH = __builtin_amdgcn_readfirstlane(cnt[n]) >> 5;   // 32-row chunks
    const uint2* cl = (const uint2*)(colbuf + n * CAP);
    const int hi4 = sub >> 2;          // which uint2 of the pair
    const int wsel = (sub >> 1) & 1;   // .x / .y
    const int sh = (sub & 1) << 4;     // 16-bit half
    uint2 p0 = cl[0], p1 = cl[1], p2 = cl[2], p3 = cl[3];
    uint2 p4 = cl[4], p5 = cl[5], p6 = cl[6], p7 = cl[7];
    for (int c = 0; c < NCH; ++c) {
        // load j covers rows j*8 .. j*8+7 ; this sub's id for load j:
        unsigned q0 = hi4 ? (wsel ? p1.y : p1.x) : (wsel ? p0.y : p0.x);
        unsigned q1 = hi4 ? (wsel ? p3.y : p3.x) : (wsel ? p2.y : p2.x);
        unsigned q2 = hi4 ? (wsel ? p5.y : p5.x) : (wsel ? p4.y : p4.x);
        unsigned q3 = hi4 ? (wsel ? p7.y : p7.x) : (wsel ? p6.y : p6.x);
        int s0 = (int)((q0 >> sh) & 0xffffu);
        int s1 = (int)((q1 >> sh) & 0xffffu);
        int s2 = (int)((q2 >> sh) & 0xffffu);
        int s3 = (int)((q3 >> sh) & 0xffffu);
        uint4 u0 = tb4[s0 * 8 + off];
        uint4 u1 = tb4[s1 * 8 + off];
        uint4 u2 = tb4[s2 * 8 + off];
        uint4 u3 = tb4[s3 * 8 + off];
        {
            const uint2* nx = cl + 8 * (c + 1);   // safe over-read within colbuf+tail
            p0 = nx[0]; p1 = nx[1]; p2 = nx[2]; p3 = nx[3];
            p4 = nx[4]; p5 = nx[5]; p6 = nx[6]; p7 = nx[7];
        }
        a0 += (blo(u0.x) + blo(u1.x)) + (blo(u2.x) + blo(u3.x));
        a1 += (bhi(u0.x) + bhi(u1.x)) + (bhi(u2.x) + bhi(u3.x));
        a2 += (blo(u0.y) + blo(u1.y)) + (blo(u2.y) + blo(u3.y));
        a3 += (bhi(u0.y) + bhi(u1.y)) + (bhi(u2.y) + bhi(u3.y));
        a4 += (blo(u0.z) + blo(u1.z)) + (blo(u2.z) + blo(u3.z));
        a5 += (bhi(u0.z) + bhi(u1.z)) + (bhi(u2.z) + bhi(u3.z));
        a6 += (blo(u0.w) + blo(u1.w)) + (blo(u2.w) + blo(u3.w));
        a7 += (bhi(u0.w) + bhi(u1.w)) + (bhi(u2.w) + bhi(u3.w));
    }
    // reduce across the 8 sub-groups (lane xor 8,16,32)
    a0 += __shfl_xor(a0, 8); a0 += __shfl_xor(a0, 16); a0 += __shfl_xor(a0, 32);
    a1 += __shfl_xor(a1, 8); a1 += __shfl_xor(a1, 16); a1 += __shfl_xor(a1, 32);
    a2 += __shfl_xor(a2, 8); a2 += __shfl_xor(a2, 16); a2 += __shfl_xor(a2, 32);
    a3 += __shfl_xor(a3, 8); a3 += __shfl_xor(a3, 16); a3 += __shfl_xor(a3, 32);
    a4 += __shfl_xor(a4, 8); a4 += __shfl_xor(a4, 16); a4 += __shfl_xor(a4, 32);
    a5 += __shfl_xor(a5, 8); a5 += __shfl_xor(a5, 16); a5 += __shfl_xor(a5, 32);
    a6 += __shfl_xor(a6, 8); a6 += __shfl_xor(a6, 16); a6 += __shfl_xor(a6, 32);
    a7 += __shfl_xor(a7, 8); a7 += __shfl_xor(a7, 16); a7 += __shfl_xor(a7, 32);
    if (sub == 0) {
        float* o = outf + (size_t)n * N_CLS + 8 * off;
        *(float4*)o       = make_float4(a0, a1, a2, a3);
        *(float4*)(o + 4) = make_float4(a4, a5, a6, a7);
    }
}

extern "C" void kernel_launch(void* const* d_in, const int* in_sizes, int n_in,
                              void* d_out, int out_size, void* d_ws, size_t ws_size,
                              hipStream_t stream) {
    const float* feat = (const float*)d_in[0];
    const float* W0   = (const float*)d_in[1];
    const float* W1   = (const float*)d_in[2];
    const float* W2   = (const float*)d_in[3];
    const int*   src  = (const int*)d_in[4];
    const int*   dst  = (const int*)d_in[5];
    float* out = (float*)d_out;

    int* coarse_cnt        = (int*)d_ws;                          // GRP*CCS ints
    int* cnt               = coarse_cnt + GRP * CCS;              // NN (+8 align pad)
    unsigned short* colbuf = (unsigned short*)(cnt + NN + 8);     // NN*CAP
    unsigned* coarse       = (unsigned*)(colbuf + (size_t)NN * CAP);  // GRP*CAPC
    unsigned* hb0          = coarse + (size_t)GRP * CAPC;         // (NN+1)*64
    unsigned* hb1          = hb0 + (size_t)(NN + 1) * 64;
    unsigned* hb2          = hb1 + (size_t)(NN + 1) * 64;         // reused as tb
    unsigned* wb0          = hb2 + (size_t)(NN + 1) * 64;         // 8192
    unsigned* wb1          = wb0 + 8192;                          // 8192
    unsigned* wb2          = wb1 + 8192;                          // 4096
    unsigned short* tb     = (unsigned short*)hb2;                // (NN+1)*64 bf16

    hipMemsetAsync(coarse_cnt, 0, GRP * CCS * sizeof(int), stream);
    prep_a<<<AB + CB + WB, 256, 0, stream>>>(src, dst, coarse_cnt, coarse, feat, hb0,
                                             W0, W1, W2, wb0, wb1, wb2);
    prep_b<<<GRP, 1024, 0, stream>>>(coarse_cnt, coarse, cnt, colbuf);

    gin_layer1<<<NN / 4, 256, 0, stream>>>((const uint4*)hb0, cnt, colbuf, wb0,
                                           (unsigned short*)hb1);
    gin_mid<<<NN / 4, 256, 0, stream>>>((const uint4*)hb1, cnt, colbuf, wb1, wb2, tb);
    agg3<<<NN / 4, 256, 0, stream>>>((const uint4*)tb, cnt, colbuf, out);
}

// Round 4
// 139.764 us; speedup vs baseline: 1.0533x; 1.0226x over previous
//
#include <hip/hip_runtime.h>
#include <hip/hip_bf16.h>

#define NN 10000
#define NE 640000
#define D_IN 128
#define D_H 128
#define N_CLS 64
#define CAP 160    // per-node capacity (ushort): mean 64 sigma 8 -> +12 sigma
#define GRP 157    // coarse groups: dst>>6 (64 nodes/group)
#define CAPC 4800  // per-group coarse capacity
#define CCS 16     // coarse_cnt stride (ints): one counter per 64B line
#define SENT 10000 // sentinel node id (zero row)
#define EPB 1024
#define AB 625     // 625*1024 == 640000
#define CB 1251    // (NN+1)*32 uint2 / 256
#define W01B 16    // blocks computing W01 = W0@W1 (f32)
#define WPB 4      // prep_b blocks packing Wp = W01@W2 (bf16 k-pairs)

// ---- bf16 helpers ----
__device__ __forceinline__ float blo(unsigned u) { return __uint_as_float(u << 16); }
__device__ __forceinline__ float bhi(unsigned u) { return __uint_as_float(u & 0xffff0000u); }
__device__ __forceinline__ unsigned short f2bf(float f) {
    unsigned u = __float_as_uint(f);
    return (unsigned short)((u + 0x7fffu + ((u >> 16) & 1u)) >> 16);
}
__device__ __forceinline__ unsigned packbf(float a, float b) {
    return (unsigned)f2bf(a) | ((unsigned)f2bf(b) << 16);
}

// ---- prep_a: coarse-bucket edges + f32->bf16 feature conv + W01 = W0@W1 (f32) ----
__global__ __launch_bounds__(256) void prep_a(const int* __restrict__ src,
                                              const int* __restrict__ dst,
                                              int* __restrict__ coarse_cnt,
                                              unsigned* __restrict__ coarse,
                                              const float* __restrict__ feat,
                                              unsigned* __restrict__ hb0,
                                              const float* __restrict__ W0,
                                              const float* __restrict__ W1,
                                              float* __restrict__ W01) {
    int bid = blockIdx.x;
    if (bid >= AB + CB) {   // ---- W01 = W0@W1, f32 (16 blocks x 256 thr = 4096 thr, 4 cols each) ----
        int t = (bid - AB - CB) * 256 + threadIdx.x;   // 0..4095
        int i = t >> 5;            // row 0..127
        int jb = (t & 31) << 2;    // col group of 4
        float c0 = 0.f, c1 = 0.f, c2 = 0.f, c3 = 0.f;
        for (int k = 0; k < 128; ++k) {
            float a = W0[i * 128 + k];
            float4 b = *(const float4*)&W1[k * 128 + jb];
            c0 += a * b.x; c1 += a * b.y; c2 += a * b.z; c3 += a * b.w;
        }
        *(float4*)&W01[i * 128 + jb] = make_float4(c0, c1, c2, c3);
        return;
    }
    if (bid >= AB) {   // ---- feature conv ----
        int t = (bid - AB) * 256 + threadIdx.x;
        if (t < NN * 32) {
            float4 f = ((const float4*)feat)[t];
            ((uint2*)hb0)[t] = make_uint2(packbf(f.x, f.y), packbf(f.z, f.w));
        } else if (t < (NN + 1) * 32) {
            ((uint2*)hb0)[t] = make_uint2(0u, 0u);
        }
        return;
    }
    __shared__ unsigned stage[EPB];
    __shared__ int hist[GRP], gbase[GRP], cur[GRP];
    const int t = threadIdx.x;
    for (int i = t; i < GRP; i += 256) hist[i] = 0;
    __syncthreads();
    const int e0 = bid * EPB;
    for (int i = t; i < EPB; i += 256) {
        int s = src[e0 + i];
        int d = dst[e0 + i];
        stage[i] = (unsigned)s | ((unsigned)d << 16);
        atomicAdd(&hist[d >> 6], 1);
    }
    __syncthreads();
    for (int i = t; i < GRP; i += 256) {
        gbase[i] = atomicAdd(&coarse_cnt[i * CCS], hist[i]);
        cur[i] = 0;
    }
    __syncthreads();
    for (int i = t; i < EPB; i += 256) {
        unsigned u = stage[i];
        int g = u >> 22;
        int r = atomicAdd(&cur[g], 1);
        coarse[g * CAPC + gbase[g] + r] = u;
    }
}

// ---- prep_b: per-group scatter into LDS-staged colbuf + Wp = W01@W2 bf16 pack ----
__global__ __launch_bounds__(1024) void prep_b(const int* __restrict__ coarse_cnt,
                                               const unsigned* __restrict__ coarse,
                                               int* __restrict__ cnt,
                                               unsigned short* __restrict__ colbuf,
                                               const float* __restrict__ W01,
                                               const float* __restrict__ W2,
                                               unsigned* __restrict__ wbp) {
    const int g = blockIdx.x;
    const int t = threadIdx.x;
    if (g >= GRP) {   // ---- Wp pack: 4 blocks x 1024 thr = 4096 pack-slots (kp,j) ----
        int s = (g - GRP) * 1024 + t;   // 0..4095
        int kp = s >> 6, j = s & 63;
        float c0 = 0.f, c1 = 0.f;
        const float* r0 = W01 + (2 * kp) * 128;
        const float* r1 = r0 + 128;
        for (int k = 0; k < 128; ++k) {
            float w2 = W2[k * 64 + j];
            c0 += r0[k] * w2;
            c1 += r1[k] * w2;
        }
        wbp[kp * 64 + j] = packbf(c0, c1);
        return;
    }
    __shared__ int cur[64];
    __shared__ unsigned short sbuf[64][CAP];   // 20480 B LDS stage for this group
    if (t < 64) cur[t] = 0;
    __syncthreads();
    const int m = coarse_cnt[g * CCS];
    const unsigned* cb = coarse + g * CAPC;
    for (int i = t; i < m; i += 1024) {
        unsigned u = cb[i];
        int s = (int)(u & 0xFFFFu);
        int dl = (int)(u >> 16) - (g << 6);
        int r = atomicAdd(&cur[dl], 1);
        sbuf[dl][r] = (unsigned short)s;       // 2B scatter stays in LDS
    }
    __syncthreads();
    if (t < 64) {
        int n = (g << 6) + t;
        if (n < NN) {
            int c = cur[t];
            int pad = (32 - (c & 31)) & 31;    // pad to x32 for the unrolled gather
            for (int k = 0; k < pad; ++k) sbuf[t][c + k] = (unsigned short)SENT;
            cnt[n] = c + pad;
        }
    }
    __syncthreads();
    // coalesced copy-out: 64 nodes x (CAP/8 = 20) uint4
    const uint4* s4 = (const uint4*)sbuf;
    for (int idx = t; idx < 64 * (CAP / 8); idx += 1024) {
        int node = (g << 6) + (idx / (CAP / 8));
        if (node < NN)
            ((uint4*)colbuf)[(size_t)node * (CAP / 8) + (idx % (CAP / 8))] = s4[idx];
    }
}

// ---- stage 1: t = (B h0) @ Wp  (gather 128-d + single 128->64 GEMM) -> bf16 ----
__global__ __launch_bounds__(256, 4) void proj1(const uint4* __restrict__ hb4,
                                                const int* __restrict__ cnt,
                                                const unsigned short* __restrict__ colbuf,
                                                const unsigned* __restrict__ Wbp,
                                                unsigned short* __restrict__ tb) {
    constexpr int M = 4;
    __shared__ float xs[M][D_H];
    const int base = blockIdx.x * M;
    const int tid = threadIdx.x;
    const int wave = tid >> 6;
    const int lane = tid & 63;
    const int sub = lane >> 4;
    const int off = lane & 15;

    const int n = __builtin_amdgcn_readfirstlane(base + wave);
    float a0, a1, a2, a3, a4, a5, a6, a7;
    if (sub == 0) {           // own row (eps=0: h + agg)
        uint4 u = hb4[n * 16 + off];
        a0 = blo(u.x); a1 = bhi(u.x); a2 = blo(u.y); a3 = bhi(u.y);
        a4 = blo(u.z); a5 = bhi(u.z); a6 = blo(u.w); a7 = bhi(u.w);
    } else {
        a0 = a1 = a2 = a3 = a4 = a5 = a6 = a7 = 0.f;
    }
    const int NCH = __builtin_amdgcn_readfirstlane(cnt[n]) >> 5;
    const uint2* cl = (const uint2*)(colbuf + n * CAP);
    const int sh = (sub & 1) << 4;
    uint2 p0 = cl[0], p1 = cl[1], p2 = cl[2], p3 = cl[3];
    uint2 p4 = cl[4], p5 = cl[5], p6 = cl[6], p7 = cl[7];
    for (int c = 0; c < NCH; ++c) {
        unsigned w0 = (sub & 2) ? p0.y : p0.x;
        unsigned w1 = (sub & 2) ? p1.y : p1.x;
        unsigned w2 = (sub & 2) ? p2.y : p2.x;
        unsigned w3 = (sub & 2) ? p3.y : p3.x;
        unsigned w4 = (sub & 2) ? p4.y : p4.x;
        unsigned w5 = (sub & 2) ? p5.y : p5.x;
        unsigned w6 = (sub & 2) ? p6.y : p6.x;
        unsigned w7 = (sub & 2) ? p7.y : p7.x;
        int s0 = (int)((w0 >> sh) & 0xffffu);
        int s1 = (int)((w1 >> sh) & 0xffffu);
        int s2 = (int)((w2 >> sh) & 0xffffu);
        int s3 = (int)((w3 >> sh) & 0xffffu);
        int s4 = (int)((w4 >> sh) & 0xffffu);
        int s5 = (int)((w5 >> sh) & 0xffffu);
        int s6 = (int)((w6 >> sh) & 0xffffu);
        int s7 = (int)((w7 >> sh) & 0xffffu);
        uint4 u0 = hb4[s0 * 16 + off];
        uint4 u1 = hb4[s1 * 16 + off];
        uint4 u2 = hb4[s2 * 16 + off];
        uint4 u3 = hb4[s3 * 16 + off];
        uint4 u4 = hb4[s4 * 16 + off];
        uint4 u5 = hb4[s5 * 16 + off];
        uint4 u6 = hb4[s6 * 16 + off];
        uint4 u7 = hb4[s7 * 16 + off];
        {
            const uint2* nx = cl + 8 * (c + 1);   // safe over-read within CAP region
            p0 = nx[0]; p1 = nx[1]; p2 = nx[2]; p3 = nx[3];
            p4 = nx[4]; p5 = nx[5]; p6 = nx[6]; p7 = nx[7];
        }
        a0 += ((blo(u0.x) + blo(u1.x)) + (blo(u2.x) + blo(u3.x)))
            + ((blo(u4.x) + blo(u5.x)) + (blo(u6.x) + blo(u7.x)));
        a1 += ((bhi(u0.x) + bhi(u1.x)) + (bhi(u2.x) + bhi(u3.x)))
            + ((bhi(u4.x) + bhi(u5.x)) + (bhi(u6.x) + bhi(u7.x)));
        a2 += ((blo(u0.y) + blo(u1.y)) + (blo(u2.y) + blo(u3.y)))
            + ((blo(u4.y) + blo(u5.y)) + (blo(u6.y) + blo(u7.y)));
        a3 += ((bhi(u0.y) + bhi(u1.y)) + (bhi(u2.y) + bhi(u3.y)))
            + ((bhi(u4.y) + bhi(u5.y)) + (bhi(u6.y) + bhi(u7.y)));
        a4 += ((blo(u0.z) + blo(u1.z)) + (blo(u2.z) + blo(u3.z)))
            + ((blo(u4.z) + blo(u5.z)) + (blo(u6.z) + blo(u7.z)));
        a5 += ((bhi(u0.z) + bhi(u1.z)) + (bhi(u2.z) + bhi(u3.z)))
            + ((bhi(u4.z) + bhi(u5.z)) + (bhi(u6.z) + bhi(u7.z)));
        a6 += ((blo(u0.w) + blo(u1.w)) + (blo(u2.w) + blo(u3.w)))
            + ((blo(u4.w) + blo(u5.w)) + (blo(u6.w) + blo(u7.w)));
        a7 += ((bhi(u0.w) + bhi(u1.w)) + (bhi(u2.w) + bhi(u3.w)))
            + ((bhi(u4.w) + bhi(u5.w)) + (bhi(u6.w) + bhi(u7.w)));
    }
    a0 += __shfl_xor(a0, 16); a0 += __shfl_xor(a0, 32);
    a1 += __shfl_xor(a1, 16); a1 += __shfl_xor(a1, 32);
    a2 += __shfl_xor(a2, 16); a2 += __shfl_xor(a2, 32);
    a3 += __shfl_xor(a3, 16); a3 += __shfl_xor(a3, 32);
    a4 += __shfl_xor(a4, 16); a4 += __shfl_xor(a4, 32);
    a5 += __shfl_xor(a5, 16); a5 += __shfl_xor(a5, 32);
    a6 += __shfl_xor(a6, 16); a6 += __shfl_xor(a6, 32);
    a7 += __shfl_xor(a7, 16); a7 += __shfl_xor(a7, 32);
    if (sub == 0) {
        *(float4*)&xs[wave][8 * off]     = make_float4(a0, a1, a2, a3);
        *(float4*)&xs[wave][8 * off + 4] = make_float4(a4, a5, a6, a7);
    }
    __syncthreads();

    // ---- GEMM: t = x @ Wp (128 -> 64), one node per wave ----
    const int j = tid & 63;
    float acc = 0.f;
    for (int k = 0; k < D_H; k += 4) {
        unsigned wp0 = Wbp[(k >> 1) * 64 + j];
        unsigned wp1 = Wbp[((k >> 1) + 1) * 64 + j];
        float w0 = blo(wp0), w1 = bhi(wp0), w2 = blo(wp1), w3 = bhi(wp1);
        float4 xv = *(const float4*)&xs[wave][k];
        acc += xv.x * w0 + xv.y * w1 + xv.z * w2 + xv.w * w3;
    }
    tb[(size_t)(base + wave) * 64 + j] = f2bf(acc);
    if (blockIdx.x == 0 && tid < 16) {
        ((uint2*)(tb + (size_t)SENT * 64))[tid] = make_uint2(0u, 0u);
    }
}

// ---- stage 2: t2 = B t  (pure 64-d aggregate, 128B/row, 8 rows/instr) -> bf16 ----
__global__ __launch_bounds__(256, 4) void agg64b(const uint4* __restrict__ tb4,
                                                 const int* __restrict__ cnt,
                                                 const unsigned short* __restrict__ colbuf,
                                                 unsigned short* __restrict__ tb2) {
    constexpr int M = 4;
    const int base = blockIdx.x * M;
    const int tid = threadIdx.x;
    const int wave = tid >> 6;
    const int lane = tid & 63;
    const int sub = lane >> 3;     // 0..7 : 8 rows per load instruction
    const int off = lane & 7;      // 16B slice within a 128B row

    const int n = __builtin_amdgcn_readfirstlane(base + wave);
    float a0, a1, a2, a3, a4, a5, a6, a7;
    if (sub == 0) {                // own row (eps=0)
        uint4 u = tb4[n * 8 + off];
        a0 = blo(u.x); a1 = bhi(u.x); a2 = blo(u.y); a3 = bhi(u.y);
        a4 = blo(u.z); a5 = bhi(u.z); a6 = blo(u.w); a7 = bhi(u.w);
    } else {
        a0 = a1 = a2 = a3 = a4 = a5 = a6 = a7 = 0.f;
    }
    const int NCH = __builtin_amdgcn_readfirstlane(cnt[n]) >> 5;   // 32-row chunks
    const uint2* cl = (const uint2*)(colbuf + n * CAP);
    const int hi4 = sub >> 2;
    const int wsel = (sub >> 1) & 1;
    const int sh = (sub & 1) << 4;
    uint2 p0 = cl[0], p1 = cl[1], p2 = cl[2], p3 = cl[3];
    uint2 p4 = cl[4], p5 = cl[5], p6 = cl[6], p7 = cl[7];
    for (int c = 0; c < NCH; ++c) {
        unsigned q0 = hi4 ? (wsel ? p1.y : p1.x) : (wsel ? p0.y : p0.x);
        unsigned q1 = hi4 ? (wsel ? p3.y : p3.x) : (wsel ? p2.y : p2.x);
        unsigned q2 = hi4 ? (wsel ? p5.y : p5.x) : (wsel ? p4.y : p4.x);
        unsigned q3 = hi4 ? (wsel ? p7.y : p7.x) : (wsel ? p6.y : p6.x);
        int s0 = (int)((q0 >> sh) & 0xffffu);
        int s1 = (int)((q1 >> sh) & 0xffffu);
        int s2 = (int)((q2 >> sh) & 0xffffu);
        int s3 = (int)((q3 >> sh) & 0xffffu);
        uint4 u0 = tb4[s0 * 8 + off];
        uint4 u1 = tb4[s1 * 8 + off];
        uint4 u2 = tb4[s2 * 8 + off];
        uint4 u3 = tb4[s3 * 8 + off];
        {
            const uint2* nx = cl + 8 * (c + 1);
            p0 = nx[0]; p1 = nx[1]; p2 = nx[2]; p3 = nx[3];
            p4 = nx[4]; p5 = nx[5]; p6 = nx[6]; p7 = nx[7];
        }
        a0 += (blo(u0.x) + blo(u1.x)) + (blo(u2.x) + blo(u3.x));
        a1 += (bhi(u0.x) + bhi(u1.x)) + (bhi(u2.x) + bhi(u3.x));
        a2 += (blo(u0.y) + blo(u1.y)) + (blo(u2.y) + blo(u3.y));
        a3 += (bhi(u0.y) + bhi(u1.y)) + (bhi(u2.y) + bhi(u3.y));
        a4 += (blo(u0.z) + blo(u1.z)) + (blo(u2.z) + blo(u3.z));
        a5 += (bhi(u0.z) + bhi(u1.z)) + (bhi(u2.z) + bhi(u3.z));
        a6 += (blo(u0.w) + blo(u1.w)) + (blo(u2.w) + blo(u3.w));
        a7 += (bhi(u0.w) + bhi(u1.w)) + (bhi(u2.w) + bhi(u3.w));
    }
    a0 += __shfl_xor(a0, 8); a0 += __shfl_xor(a0, 16); a0 += __shfl_xor(a0, 32);
    a1 += __shfl_xor(a1, 8); a1 += __shfl_xor(a1, 16); a1 += __shfl_xor(a1, 32);
    a2 += __shfl_xor(a2, 8); a2 += __shfl_xor(a2, 16); a2 += __shfl_xor(a2, 32);
    a3 += __shfl_xor(a3, 8); a3 += __shfl_xor(a3, 16); a3 += __shfl_xor(a3, 32);
    a4 += __shfl_xor(a4, 8); a4 += __shfl_xor(a4, 16); a4 += __shfl_xor(a4, 32);
    a5 += __shfl_xor(a5, 8); a5 += __shfl_xor(a5, 16); a5 += __shfl_xor(a5, 32);
    a6 += __shfl_xor(a6, 8); a6 += __shfl_xor(a6, 16); a6 += __shfl_xor(a6, 32);
    a7 += __shfl_xor(a7, 8); a7 += __shfl_xor(a7, 16); a7 += __shfl_xor(a7, 32);
    if (sub == 0) {
        unsigned short* o = tb2 + (size_t)n * 64 + 8 * off;
        *(uint4*)o = make_uint4(packbf(a0, a1), packbf(a2, a3),
                                packbf(a4, a5), packbf(a6, a7));
    }
    if (blockIdx.x == 0 && tid < 16) {
        ((uint2*)(tb2 + (size_t)SENT * 64))[tid] = make_uint2(0u, 0u);
    }
}

// ---- stage 3: out = B t2  (64-d aggregate, f32 output) ----
__global__ __launch_bounds__(256, 4) void agg64f(const uint4* __restrict__ tb4,
                                                 const int* __restrict__ cnt,
                                                 const unsigned short* __restrict__ colbuf,
                                                 float* __restrict__ outf) {
    constexpr int M = 4;
    const int base = blockIdx.x * M;
    const int tid = threadIdx.x;
    const int wave = tid >> 6;
    const int lane = tid & 63;
    const int sub = lane >> 3;
    const int off = lane & 7;

    const int n = __builtin_amdgcn_readfirstlane(base + wave);
    float a0, a1, a2, a3, a4, a5, a6, a7;
    if (sub == 0) {
        uint4 u = tb4[n * 8 + off];
        a0 = blo(u.x); a1 = bhi(u.x); a2 = blo(u.y); a3 = bhi(u.y);
        a4 = blo(u.z); a5 = bhi(u.z); a6 = blo(u.w); a7 = bhi(u.w);
    } else {
        a0 = a1 = a2 = a3 = a4 = a5 = a6 = a7 = 0.f;
    }
    const int NCH = __builtin_amdgcn_readfirstlane(cnt[n]) >> 5;
    const uint2* cl = (const uint2*)(colbuf + n * CAP);
    const int hi4 = sub >> 2;
    const int wsel = (sub >> 1) & 1;
    const int sh = (sub & 1) << 4;
    uint2 p0 = cl[0], p1 = cl[1], p2 = cl[2], p3 = cl[3];
    uint2 p4 = cl[4], p5 = cl[5], p6 = cl[6], p7 = cl[7];
    for (int c = 0; c < NCH; ++c) {
        unsigned q0 = hi4 ? (wsel ? p1.y : p1.x) : (wsel ? p0.y : p0.x);
        unsigned q1 = hi4 ? (wsel ? p3.y : p3.x) : (wsel ? p2.y : p2.x);
        unsigned q2 = hi4 ? (wsel ? p5.y : p5.x) : (wsel ? p4.y : p4.x);
        unsigned q3 = hi4 ? (wsel ? p7.y : p7.x) : (wsel ? p6.y : p6.x);
        int s0 = (int)((q0 >> sh) & 0xffffu);
        int s1 = (int)((q1 >> sh) & 0xffffu);
        int s2 = (int)((q2 >> sh) & 0xffffu);
        int s3 = (int)((q3 >> sh) & 0xffffu);
        uint4 u0 = tb4[s0 * 8 + off];
        uint4 u1 = tb4[s1 * 8 + off];
        uint4 u2 = tb4[s2 * 8 + off];
        uint4 u3 = tb4[s3 * 8 + off];
        {
            const uint2* nx = cl + 8 * (c + 1);
            p0 = nx[0]; p1 = nx[1]; p2 = nx[2]; p3 = nx[3];
            p4 = nx[4]; p5 = nx[5]; p6 = nx[6]; p7 = nx[7];
        }
        a0 += (blo(u0.x) + blo(u1.x)) + (blo(u2.x) + blo(u3.x));
        a1 += (bhi(u0.x) + bhi(u1.x)) + (bhi(u2.x) + bhi(u3.x));
        a2 += (blo(u0.y) + blo(u1.y)) + (blo(u2.y) + blo(u3.y));
        a3 += (bhi(u0.y) + bhi(u1.y)) + (bhi(u2.y) + bhi(u3.y));
        a4 += (blo(u0.z) + blo(u1.z)) + (blo(u2.z) + blo(u3.z));
        a5 += (bhi(u0.z) + bhi(u1.z)) + (bhi(u2.z) + bhi(u3.z));
        a6 += (blo(u0.w) + blo(u1.w)) + (blo(u2.w) + blo(u3.w));
        a7 += (bhi(u0.w) + bhi(u1.w)) + (bhi(u2.w) + bhi(u3.w));
    }
    a0 += __shfl_xor(a0, 8); a0 += __shfl_xor(a0, 16); a0 += __shfl_xor(a0, 32);
    a1 += __shfl_xor(a1, 8); a1 += __shfl_xor(a1, 16); a1 += __shfl_xor(a1, 32);
    a2 += __shfl_xor(a2, 8); a2 += __shfl_xor(a2, 16); a2 += __shfl_xor(a2, 32);
    a3 += __shfl_xor(a3, 8); a3 += __shfl_xor(a3, 16); a3 += __shfl_xor(a3, 32);
    a4 += __shfl_xor(a4, 8); a4 += __shfl_xor(a4, 16); a4 += __shfl_xor(a4, 32);
    a5 += __shfl_xor(a5, 8); a5 += __shfl_xor(a5, 16); a5 += __shfl_xor(a5, 32);
    a6 += __shfl_xor(a6, 8); a6 += __shfl_xor(a6, 16); a6 += __shfl_xor(a6, 32);
    a7 += __shfl_xor(a7, 8); a7 += __shfl_xor(a7, 16); a7 += __shfl_xor(a7, 32);
    if (sub == 0) {
        float* o = outf + (size_t)n * N_CLS + 8 * off;
        *(float4*)o       = make_float4(a0, a1, a2, a3);
        *(float4*)(o + 4) = make_float4(a4, a5, a6, a7);
    }
}

extern "C" void kernel_launch(void* const* d_in, const int* in_sizes, int n_in,
                              void* d_out, int out_size, void* d_ws, size_t ws_size,
                              hipStream_t stream) {
    const float* feat = (const float*)d_in[0];
    const float* W0   = (const float*)d_in[1];
    const float* W1   = (const float*)d_in[2];
    const float* W2   = (const float*)d_in[3];
    const int*   src  = (const int*)d_in[4];
    const int*   dst  = (const int*)d_in[5];
    float* out = (float*)d_out;

    int* coarse_cnt        = (int*)d_ws;                          // GRP*CCS ints
    int* cnt               = coarse_cnt + GRP * CCS;              // NN (+8 align pad)
    unsigned short* colbuf = (unsigned short*)(cnt + NN + 8);     // NN*CAP
    unsigned* coarse       = (unsigned*)(colbuf + (size_t)NN * CAP);  // GRP*CAPC
    unsigned* hb0          = coarse + (size_t)GRP * CAPC;         // (NN+1)*64
    unsigned* tbu          = hb0 + (size_t)(NN + 1) * 64;         // (NN+1)*32 (64-d bf16)
    unsigned* tb2u         = tbu + (size_t)(NN + 1) * 32;         // (NN+1)*32
    float* W01             = (float*)(tb2u + (size_t)(NN + 1) * 32); // 16384 f32
    unsigned* wbp          = (unsigned*)(W01 + 16384);            // 4096
    unsigned short* tb     = (unsigned short*)tbu;
    unsigned short* tb2    = (unsigned short*)tb2u;

    hipMemsetAsync(coarse_cnt, 0, GRP * CCS * sizeof(int), stream);
    prep_a<<<AB + CB + W01B, 256, 0, stream>>>(src, dst, coarse_cnt, coarse, feat, hb0,
                                               W0, W1, W01);
    prep_b<<<GRP + WPB, 1024, 0, stream>>>(coarse_cnt, coarse, cnt, colbuf,
                                           W01, W2, wbp);

    proj1<<<NN / 4, 256, 0, stream>>>((const uint4*)hb0, cnt, colbuf, wbp, tb);
    agg64b<<<NN / 4, 256, 0, stream>>>((const uint4*)tb, cnt, colbuf, tb2);
    agg64f<<<NN / 4, 256, 0, stream>>>((const uint4*)tb2, cnt, colbuf, out);
}

// Round 5
// 137.174 us; speedup vs baseline: 1.0732x; 1.0189x over previous
//
#include <hip/hip_runtime.h>
#include <hip/hip_bf16.h>

#define NN 10000
#define NE 640000
#define D_IN 128
#define D_H 128
#define N_CLS 64
#define CAP 160    // per-node capacity (ushort): mean 64 sigma 8 -> +12 sigma
#define GRP 157    // coarse groups: dst>>6 (64 nodes/group)
#define CAPC 4800  // per-group coarse capacity
#define CCS 16     // coarse_cnt stride (ints): one counter per 64B line
#define SENT 10000 // sentinel node id (zero row)
#define EPB 1024
#define AB 625     // 625*1024 == 640000
#define W01B 16    // blocks computing W01 = W0@W1 (f32)
#define WPB 4      // prep_b blocks packing Wp = W01@W2 (bf16 k-pairs)

// ---- bf16 helpers ----
__device__ __forceinline__ float blo(unsigned u) { return __uint_as_float(u << 16); }
__device__ __forceinline__ float bhi(unsigned u) { return __uint_as_float(u & 0xffff0000u); }
__device__ __forceinline__ unsigned short f2bf(float f) {
    unsigned u = __float_as_uint(f);
    return (unsigned short)((u + 0x7fffu + ((u >> 16) & 1u)) >> 16);
}
__device__ __forceinline__ unsigned packbf(float a, float b) {
    return (unsigned)f2bf(a) | ((unsigned)f2bf(b) << 16);
}

// ---- prep_a: coarse-bucket edges + W01 = W0@W1 (f32) ----
__global__ __launch_bounds__(256) void prep_a(const int* __restrict__ src,
                                              const int* __restrict__ dst,
                                              int* __restrict__ coarse_cnt,
                                              unsigned* __restrict__ coarse,
                                              const float* __restrict__ W0,
                                              const float* __restrict__ W1,
                                              float* __restrict__ W01) {
    int bid = blockIdx.x;
    if (bid >= AB) {   // ---- W01 = W0@W1, f32 (16 blocks x 256 thr, 4 cols each) ----
        int t = (bid - AB) * 256 + threadIdx.x;   // 0..4095
        int i = t >> 5;            // row 0..127
        int jb = (t & 31) << 2;    // col group of 4
        float c0 = 0.f, c1 = 0.f, c2 = 0.f, c3 = 0.f;
        for (int k = 0; k < 128; ++k) {
            float a = W0[i * 128 + k];
            float4 b = *(const float4*)&W1[k * 128 + jb];
            c0 += a * b.x; c1 += a * b.y; c2 += a * b.z; c3 += a * b.w;
        }
        *(float4*)&W01[i * 128 + jb] = make_float4(c0, c1, c2, c3);
        return;
    }
    __shared__ unsigned stage[EPB];
    __shared__ int hist[GRP], gbase[GRP], cur[GRP];
    const int t = threadIdx.x;
    for (int i = t; i < GRP; i += 256) hist[i] = 0;
    __syncthreads();
    const int e0 = bid * EPB;
    for (int i = t; i < EPB; i += 256) {
        int s = src[e0 + i];
        int d = dst[e0 + i];
        stage[i] = (unsigned)s | ((unsigned)d << 16);
        atomicAdd(&hist[d >> 6], 1);
    }
    __syncthreads();
    for (int i = t; i < GRP; i += 256) {
        gbase[i] = atomicAdd(&coarse_cnt[i * CCS], hist[i]);
        cur[i] = 0;
    }
    __syncthreads();
    for (int i = t; i < EPB; i += 256) {
        unsigned u = stage[i];
        int g = u >> 22;
        int r = atomicAdd(&cur[g], 1);
        coarse[g * CAPC + gbase[g] + r] = u;
    }
}

// ---- prep_b: per-group scatter into LDS-staged colbuf + Wp = W01@W2 bf16 pack ----
__global__ __launch_bounds__(1024) void prep_b(const int* __restrict__ coarse_cnt,
                                               const unsigned* __restrict__ coarse,
                                               int* __restrict__ cnt,
                                               unsigned short* __restrict__ colbuf,
                                               const float* __restrict__ W01,
                                               const float* __restrict__ W2,
                                               unsigned* __restrict__ wbp) {
    const int g = blockIdx.x;
    const int t = threadIdx.x;
    if (g >= GRP) {   // ---- Wp pack: 4 blocks x 1024 thr = 4096 pack-slots (kp,j) ----
        int s = (g - GRP) * 1024 + t;   // 0..4095
        int kp = s >> 6, j = s & 63;
        float c0 = 0.f, c1 = 0.f;
        const float* r0 = W01 + (2 * kp) * 128;
        const float* r1 = r0 + 128;
        for (int k = 0; k < 128; ++k) {
            float w2 = W2[k * 64 + j];
            c0 += r0[k] * w2;
            c1 += r1[k] * w2;
        }
        wbp[kp * 64 + j] = packbf(c0, c1);
        return;
    }
    __shared__ int cur[64];
    __shared__ unsigned short sbuf[64][CAP];   // 20480 B LDS stage for this group
    if (t < 64) cur[t] = 0;
    __syncthreads();
    const int m = coarse_cnt[g * CCS];
    const unsigned* cb = coarse + g * CAPC;
    for (int i = t; i < m; i += 1024) {
        unsigned u = cb[i];
        int s = (int)(u & 0xFFFFu);
        int dl = (int)(u >> 16) - (g << 6);
        int r = atomicAdd(&cur[dl], 1);
        sbuf[dl][r] = (unsigned short)s;       // 2B scatter stays in LDS
    }
    __syncthreads();
    if (t < 64) {
        int n = (g << 6) + t;
        if (n < NN) {
            int c = cur[t];
            int pad = (32 - (c & 31)) & 31;    // pad to x32 for the unrolled gather
            for (int k = 0; k < pad; ++k) sbuf[t][c + k] = (unsigned short)SENT;
            cnt[n] = c + pad;
        }
    }
    __syncthreads();
    // coalesced copy-out: 64 nodes x (CAP/8 = 20) uint4
    const uint4* s4 = (const uint4*)sbuf;
    for (int idx = t; idx < 64 * (CAP / 8); idx += 1024) {
        int node = (g << 6) + (idx / (CAP / 8));
        if (node < NN)
            ((uint4*)colbuf)[(size_t)node * (CAP / 8) + (idx % (CAP / 8))] = s4[idx];
    }
}

// ---- gemm0: g0 = feat @ Wp (dense, coalesced; 128 -> 64, bf16 out) ----
__global__ __launch_bounds__(256, 4) void gemm0(const float* __restrict__ feat,
                                                const unsigned* __restrict__ Wbp,
                                                unsigned short* __restrict__ g0) {
    __shared__ float xs[4][128];
    const int tid = threadIdx.x;
    const int wave = tid >> 6;
    const int lane = tid & 63;
    const int n = blockIdx.x * 4 + wave;
    float2 f = *(const float2*)&feat[(size_t)n * 128 + lane * 2];
    xs[wave][lane * 2]     = f.x;
    xs[wave][lane * 2 + 1] = f.y;
    __syncthreads();
    const int j = lane;
    float acc = 0.f;
    for (int k = 0; k < 128; k += 4) {
        unsigned wp0 = Wbp[(k >> 1) * 64 + j];
        unsigned wp1 = Wbp[((k >> 1) + 1) * 64 + j];
        float4 xv = *(const float4*)&xs[wave][k];
        acc += xv.x * blo(wp0) + xv.y * bhi(wp0) + xv.z * blo(wp1) + xv.w * bhi(wp1);
    }
    g0[(size_t)n * 64 + j] = f2bf(acc);
    if (blockIdx.x == 0 && tid < 16) {
        ((uint2*)(g0 + (size_t)SENT * 64))[tid] = make_uint2(0u, 0u);
    }
}

// ---- 64-d aggregate: out_row(n) = in_row(n) + sum_neighbors in_row  -> bf16 ----
__global__ __launch_bounds__(256, 4) void agg64b(const uint4* __restrict__ tb4,
                                                 const int* __restrict__ cnt,
                                                 const unsigned short* __restrict__ colbuf,
                                                 unsigned short* __restrict__ tb2) {
    constexpr int M = 4;
    const int base = blockIdx.x * M;
    const int tid = threadIdx.x;
    const int wave = tid >> 6;
    const int lane = tid & 63;
    const int sub = lane >> 3;     // 0..7 : 8 rows per load instruction
    const int off = lane & 7;      // 16B slice within a 128B row

    const int n = __builtin_amdgcn_readfirstlane(base + wave);
    float a0, a1, a2, a3, a4, a5, a6, a7;
    if (sub == 0) {                // own row (eps=0)
        uint4 u = tb4[n * 8 + off];
        a0 = blo(u.x); a1 = bhi(u.x); a2 = blo(u.y); a3 = bhi(u.y);
        a4 = blo(u.z); a5 = bhi(u.z); a6 = blo(u.w); a7 = bhi(u.w);
    } else {
        a0 = a1 = a2 = a3 = a4 = a5 = a6 = a7 = 0.f;
    }
    const int NCH = __builtin_amdgcn_readfirstlane(cnt[n]) >> 5;   // 32-row chunks
    const uint2* cl = (const uint2*)(colbuf + n * CAP);
    const int hi4 = sub >> 2;
    const int wsel = (sub >> 1) & 1;
    const int sh = (sub & 1) << 4;
    uint2 p0 = cl[0], p1 = cl[1], p2 = cl[2], p3 = cl[3];
    uint2 p4 = cl[4], p5 = cl[5], p6 = cl[6], p7 = cl[7];
    for (int c = 0; c < NCH; ++c) {
        unsigned q0 = hi4 ? (wsel ? p1.y : p1.x) : (wsel ? p0.y : p0.x);
        unsigned q1 = hi4 ? (wsel ? p3.y : p3.x) : (wsel ? p2.y : p2.x);
        unsigned q2 = hi4 ? (wsel ? p5.y : p5.x) : (wsel ? p4.y : p4.x);
        unsigned q3 = hi4 ? (wsel ? p7.y : p7.x) : (wsel ? p6.y : p6.x);
        int s0 = (int)((q0 >> sh) & 0xffffu);
        int s1 = (int)((q1 >> sh) & 0xffffu);
        int s2 = (int)((q2 >> sh) & 0xffffu);
        int s3 = (int)((q3 >> sh) & 0xffffu);
        uint4 u0 = tb4[s0 * 8 + off];
        uint4 u1 = tb4[s1 * 8 + off];
        uint4 u2 = tb4[s2 * 8 + off];
        uint4 u3 = tb4[s3 * 8 + off];
        {
            const uint2* nx = cl + 8 * (c + 1);   // safe over-read within CAP region
            p0 = nx[0]; p1 = nx[1]; p2 = nx[2]; p3 = nx[3];
            p4 = nx[4]; p5 = nx[5]; p6 = nx[6]; p7 = nx[7];
        }
        a0 += (blo(u0.x) + blo(u1.x)) + (blo(u2.x) + blo(u3.x));
        a1 += (bhi(u0.x) + bhi(u1.x)) + (bhi(u2.x) + bhi(u3.x));
        a2 += (blo(u0.y) + blo(u1.y)) + (blo(u2.y) + blo(u3.y));
        a3 += (bhi(u0.y) + bhi(u1.y)) + (bhi(u2.y) + bhi(u3.y));
        a4 += (blo(u0.z) + blo(u1.z)) + (blo(u2.z) + blo(u3.z));
        a5 += (bhi(u0.z) + bhi(u1.z)) + (bhi(u2.z) + bhi(u3.z));
        a6 += (blo(u0.w) + blo(u1.w)) + (blo(u2.w) + blo(u3.w));
        a7 += (bhi(u0.w) + bhi(u1.w)) + (bhi(u2.w) + bhi(u3.w));
    }
    a0 += __shfl_xor(a0, 8); a0 += __shfl_xor(a0, 16); a0 += __shfl_xor(a0, 32);
    a1 += __shfl_xor(a1, 8); a1 += __shfl_xor(a1, 16); a1 += __shfl_xor(a1, 32);
    a2 += __shfl_xor(a2, 8); a2 += __shfl_xor(a2, 16); a2 += __shfl_xor(a2, 32);
    a3 += __shfl_xor(a3, 8); a3 += __shfl_xor(a3, 16); a3 += __shfl_xor(a3, 32);
    a4 += __shfl_xor(a4, 8); a4 += __shfl_xor(a4, 16); a4 += __shfl_xor(a4, 32);
    a5 += __shfl_xor(a5, 8); a5 += __shfl_xor(a5, 16); a5 += __shfl_xor(a5, 32);
    a6 += __shfl_xor(a6, 8); a6 += __shfl_xor(a6, 16); a6 += __shfl_xor(a6, 32);
    a7 += __shfl_xor(a7, 8); a7 += __shfl_xor(a7, 16); a7 += __shfl_xor(a7, 32);
    if (sub == 0) {
        unsigned short* o = tb2 + (size_t)n * 64 + 8 * off;
        *(uint4*)o = make_uint4(packbf(a0, a1), packbf(a2, a3),
                                packbf(a4, a5), packbf(a6, a7));
    }
    if (blockIdx.x == 0 && tid < 16) {
        ((uint2*)(tb2 + (size_t)SENT * 64))[tid] = make_uint2(0u, 0u);
    }
}

// ---- final 64-d aggregate: f32 output ----
__global__ __launch_bounds__(256, 4) void agg64f(const uint4* __restrict__ tb4,
                                                 const int* __restrict__ cnt,
                                                 const unsigned short* __restrict__ colbuf,
                                                 float* __restrict__ outf) {
    constexpr int M = 4;
    const int base = blockIdx.x * M;
    const int tid = threadIdx.x;
    const int wave = tid >> 6;
    const int lane = tid & 63;
    const int sub = lane >> 3;
    const int off = lane & 7;

    const int n = __builtin_amdgcn_readfirstlane(base + wave);
    float a0, a1, a2, a3, a4, a5, a6, a7;
    if (sub == 0) {
        uint4 u = tb4[n * 8 + off];
        a0 = blo(u.x); a1 = bhi(u.x); a2 = blo(u.y); a3 = bhi(u.y);
        a4 = blo(u.z); a5 = bhi(u.z); a6 = blo(u.w); a7 = bhi(u.w);
    } else {
        a0 = a1 = a2 = a3 = a4 = a5 = a6 = a7 = 0.f;
    }
    const int NCH = __builtin_amdgcn_readfirstlane(cnt[n]) >> 5;
    const uint2* cl = (const uint2*)(colbuf + n * CAP);
    const int hi4 = sub >> 2;
    const int wsel = (sub >> 1) & 1;
    const int sh = (sub & 1) << 4;
    uint2 p0 = cl[0], p1 = cl[1], p2 = cl[2], p3 = cl[3];
    uint2 p4 = cl[4], p5 = cl[5], p6 = cl[6], p7 = cl[7];
    for (int c = 0; c < NCH; ++c) {
        unsigned q0 = hi4 ? (wsel ? p1.y : p1.x) : (wsel ? p0.y : p0.x);
        unsigned q1 = hi4 ? (wsel ? p3.y : p3.x) : (wsel ? p2.y : p2.x);
        unsigned q2 = hi4 ? (wsel ? p5.y : p5.x) : (wsel ? p4.y : p4.x);
        unsigned q3 = hi4 ? (wsel ? p7.y : p7.x) : (wsel ? p6.y : p6.x);
        int s0 = (int)((q0 >> sh) & 0xffffu);
        int s1 = (int)((q1 >> sh) & 0xffffu);
        int s2 = (int)((q2 >> sh) & 0xffffu);
        int s3 = (int)((q3 >> sh) & 0xffffu);
        uint4 u0 = tb4[s0 * 8 + off];
        uint4 u1 = tb4[s1 * 8 + off];
        uint4 u2 = tb4[s2 * 8 + off];
        uint4 u3 = tb4[s3 * 8 + off];
        {
            const uint2* nx = cl + 8 * (c + 1);
            p0 = nx[0]; p1 = nx[1]; p2 = nx[2]; p3 = nx[3];
            p4 = nx[4]; p5 = nx[5]; p6 = nx[6]; p7 = nx[7];
        }
        a0 += (blo(u0.x) + blo(u1.x)) + (blo(u2.x) + blo(u3.x));
        a1 += (bhi(u0.x) + bhi(u1.x)) + (bhi(u2.x) + bhi(u3.x));
        a2 += (blo(u0.y) + blo(u1.y)) + (blo(u2.y) + blo(u3.y));
        a3 += (bhi(u0.y) + bhi(u1.y)) + (bhi(u2.y) + bhi(u3.y));
        a4 += (blo(u0.z) + blo(u1.z)) + (blo(u2.z) + blo(u3.z));
        a5 += (bhi(u0.z) + bhi(u1.z)) + (bhi(u2.z) + bhi(u3.z));
        a6 += (blo(u0.w) + blo(u1.w)) + (blo(u2.w) + blo(u3.w));
        a7 += (bhi(u0.w) + bhi(u1.w)) + (bhi(u2.w) + bhi(u3.w));
    }
    a0 += __shfl_xor(a0, 8); a0 += __shfl_xor(a0, 16); a0 += __shfl_xor(a0, 32);
    a1 += __shfl_xor(a1, 8); a1 += __shfl_xor(a1, 16); a1 += __shfl_xor(a1, 32);
    a2 += __shfl_xor(a2, 8); a2 += __shfl_xor(a2, 16); a2 += __shfl_xor(a2, 32);
    a3 += __shfl_xor(a3, 8); a3 += __shfl_xor(a3, 16); a3 += __shfl_xor(a3, 32);
    a4 += __shfl_xor(a4, 8); a4 += __shfl_xor(a4, 16); a4 += __shfl_xor(a4, 32);
    a5 += __shfl_xor(a5, 8); a5 += __shfl_xor(a5, 16); a5 += __shfl_xor(a5, 32);
    a6 += __shfl_xor(a6, 8); a6 += __shfl_xor(a6, 16); a6 += __shfl_xor(a6, 32);
    a7 += __shfl_xor(a7, 8); a7 += __shfl_xor(a7, 16); a7 += __shfl_xor(a7, 32);
    if (sub == 0) {
        float* o = outf + (size_t)n * N_CLS + 8 * off;
        *(float4*)o       = make_float4(a0, a1, a2, a3);
        *(float4*)(o + 4) = make_float4(a4, a5, a6, a7);
    }
}

extern "C" void kernel_launch(void* const* d_in, const int* in_sizes, int n_in,
                              void* d_out, int out_size, void* d_ws, size_t ws_size,
                              hipStream_t stream) {
    const float* feat = (const float*)d_in[0];
    const float* W0   = (const float*)d_in[1];
    const float* W1   = (const float*)d_in[2];
    const float* W2   = (const float*)d_in[3];
    const int*   src  = (const int*)d_in[4];
    const int*   dst  = (const int*)d_in[5];
    float* out = (float*)d_out;

    int* coarse_cnt        = (int*)d_ws;                          // GRP*CCS ints
    int* cnt               = coarse_cnt + GRP * CCS;              // NN (+8 align pad)
    unsigned short* colbuf = (unsigned short*)(cnt + NN + 8);     // NN*CAP
    unsigned* coarse       = (unsigned*)(colbuf + (size_t)NN * CAP);  // GRP*CAPC
    unsigned* g0u          = coarse + (size_t)GRP * CAPC;         // (NN+1)*32 (64-d bf16)
    unsigned* tbu          = g0u + (size_t)(NN + 1) * 32;         // (NN+1)*32
    unsigned* tb2u         = tbu + (size_t)(NN + 1) * 32;         // (NN+1)*32
    float* W01             = (float*)(tb2u + (size_t)(NN + 1) * 32); // 16384 f32
    unsigned* wbp          = (unsigned*)(W01 + 16384);            // 4096
    unsigned short* g0     = (unsigned short*)g0u;
    unsigned short* tb     = (unsigned short*)tbu;
    unsigned short* tb2    = (unsigned short*)tb2u;

    hipMemsetAsync(coarse_cnt, 0, GRP * CCS * sizeof(int), stream);
    prep_a<<<AB + W01B, 256, 0, stream>>>(src, dst, coarse_cnt, coarse, W0, W1, W01);
    prep_b<<<GRP + WPB, 1024, 0, stream>>>(coarse_cnt, coarse, cnt, colbuf,
                                           W01, W2, wbp);

    gemm0<<<NN / 4, 256, 0, stream>>>(feat, wbp, g0);
    agg64b<<<NN / 4, 256, 0, stream>>>((const uint4*)g0, cnt, colbuf, tb);
    agg64b<<<NN / 4, 256, 0, stream>>>((const uint4*)tb, cnt, colbuf, tb2);
    agg64f<<<NN / 4, 256, 0, stream>>>((const uint4*)tb2, cnt, colbuf, out);
}